// Round 4
// baseline (128.195 us; speedup 1.0000x reference)
//
#include <hip/hip_runtime.h>

#define NUM_CATEGORIES 64
#define IN_DIM 1024
#define OUT_DIM 1024
#define BATCH 32
#define SEQ 512

#define BM 256
#define BN 256
#define BK 32
#define NSTEP (IN_DIM / BK)   // 32

#define LDA 40     // bf16 elems per A row (64B data + 16B pad), 16B-aligned
#define LDBW 260   // u32 words per B k-pair row (256 data + 4 pad), 16B-aligned

typedef float f32x4 __attribute__((ext_vector_type(4)));
typedef unsigned int u32x2 __attribute__((ext_vector_type(2)));
typedef unsigned int u32x4 __attribute__((ext_vector_type(4)));
typedef __bf16 bf16x8 __attribute__((ext_vector_type(8)));

__device__ inline unsigned int f2bf_rne(float f) {
    unsigned int u = __builtin_bit_cast(unsigned int, f);
    return (u + 0x7FFFu + ((u >> 16) & 1u)) >> 16;
}
__device__ inline unsigned int pack2(float lo, float hi) {
    return f2bf_rne(lo) | (f2bf_rne(hi) << 16);
}

__global__ __launch_bounds__(512, 2)
void cslinear_kernel(const float* __restrict__ x,
                     const int* __restrict__ cid,
                     const float* __restrict__ weight,
                     const float* __restrict__ bias,
                     float* __restrict__ out) {
    __shared__ unsigned short As[2][BM * LDA];          // 2 x 20 KB
    __shared__ unsigned int   Bs[2][(BK / 2) * LDBW];   // 2 x 16.25 KB

    const int t    = threadIdx.x;
    const int lane = t & 63;
    const int w    = t >> 6;      // 0..7

    // XCD-aware remap: dispatch slot s runs on XCD s%8 (round-robin).
    // Give each XCD 4 whole batches (8 blocks each) -> x/W re-reads hit same L2.
    const int s    = blockIdx.x;      // 0..255
    const int xcd  = s & 7;
    const int ixd  = s >> 3;          // 0..31 (slot within XCD)
    const int b    = xcd + 8 * (ixd >> 3);   // batches {xcd, xcd+8, xcd+16, xcd+24}
    const int j    = ixd & 7;         // 0..7 block within batch
    const int nt   = j & 3;           // 0..3
    const int mt   = j >> 2;          // 0..1

    const int c = cid[b];
    const float* Wp = weight + (size_t)c * IN_DIM * OUT_DIM + (size_t)nt * BN;
    const float* Xp = x + ((size_t)b * SEQ + (size_t)mt * BM) * IN_DIM;
    float* Op = out + ((size_t)b * SEQ + (size_t)mt * BM) * OUT_DIM + (size_t)nt * BN;

    f32x4 acc[8][4] = {};         // wave tile 128(m) x 64(n)

    const int mbase = (w >> 2) * 128;   // 0 or 128
    const int nbase = (w & 3) * 64;     // 0,64,128,192
    const int lrow  = lane & 15;
    const int lhi   = lane >> 4;        // 0..3 -> k-chunk

    // 2-deep staging register sets: loads for step ks+2 issued while
    // consuming set from step ks (in flight ~2 steps = covers HBM latency)
    f32x4 ra[2][4];
    f32x4 rb0[2][2], rb1[2][2];

    auto LOADT = [&](int ks, int sset) {
        const float* Xk = Xp + ks * BK;
        #pragma unroll
        for (int i = 0; i < 4; ++i) {
            int f   = i * 512 + t;        // 0..2047
            int row = f >> 3;             // 0..255
            int c4  = f & 7;              // 0..7
            ra[sset][i] = *reinterpret_cast<const f32x4*>(Xk + (size_t)row * IN_DIM + c4 * 4);
        }
        const float* Wk = Wp + (size_t)(ks * BK) * OUT_DIM;
        #pragma unroll
        for (int i = 0; i < 2; ++i) {
            int u  = i * 512 + t;         // 0..1023
            int kp = u >> 6;              // 0..15
            int n4 = u & 63;              // 0..63
            const float* bse = Wk + (size_t)(2 * kp) * OUT_DIM + n4 * 4;
            rb0[sset][i] = *reinterpret_cast<const f32x4*>(bse);
            rb1[sset][i] = *reinterpret_cast<const f32x4*>(bse + OUT_DIM);
        }
    };

    auto STORET = [&](int p, int sset) {
        char* AsB = reinterpret_cast<char*>(&As[p][0]);
        #pragma unroll
        for (int i = 0; i < 4; ++i) {
            int f   = i * 512 + t;
            int row = f >> 3;
            int c4  = f & 7;
            u32x2 q;
            q.x = pack2(ra[sset][i].x, ra[sset][i].y);
            q.y = pack2(ra[sset][i].z, ra[sset][i].w);
            *reinterpret_cast<u32x2*>(AsB + row * (LDA * 2) + c4 * 8) = q;
        }
        unsigned int* BsW = &Bs[p][0];
        #pragma unroll
        for (int i = 0; i < 2; ++i) {
            int u  = i * 512 + t;
            int kp = u >> 6;
            int n4 = u & 63;
            u32x4 q;
            #pragma unroll
            for (int jj = 0; jj < 4; ++jj)
                q[jj] = pack2(rb0[sset][i][jj], rb1[sset][i][jj]);
            *reinterpret_cast<u32x4*>(BsW + kp * LDBW + n4 * 4) = q;  // contiguous b128
        }
    };

    LOADT(0, 0);
    LOADT(1, 1);

    for (int ks = 0; ks < NSTEP; ++ks) {
        const int p = ks & 1;       // LDS buffer (= staging set parity)

        STORET(p, p);                          // counted vmcnt wait on 2-steps-old loads
        if (ks + 2 < NSTEP) LOADT(ks + 2, p);  // refill the just-freed set

        asm volatile("s_waitcnt lgkmcnt(0)" ::: "memory");
        __builtin_amdgcn_s_barrier();
        __builtin_amdgcn_sched_barrier(0);

        const char* AsB = reinterpret_cast<const char*>(&As[p][0]);
        const unsigned int* BsW = &Bs[p][0];

        // B frags: 4 words each are exactly the bf16x8 (k-pairs in order)
        bf16x8 bfr[4];
        #pragma unroll
        for (int ni = 0; ni < 4; ++ni) {
            int n   = nbase + ni * 16 + lrow;
            int kp0 = lhi * 4;
            u32x4 wds;
            #pragma unroll
            for (int jj = 0; jj < 4; ++jj)
                wds[jj] = BsW[(kp0 + jj) * LDBW + n];
            bfr[ni] = __builtin_bit_cast(bf16x8, wds);
        }

        #pragma unroll
        for (int mi = 0; mi < 8; ++mi) {
            int r = mbase + mi * 16 + lrow;
            bf16x8 afr = *reinterpret_cast<const bf16x8*>(AsB + r * (LDA * 2) + lhi * 16);
            #pragma unroll
            for (int ni = 0; ni < 4; ++ni)
                acc[mi][ni] = __builtin_amdgcn_mfma_f32_16x16x32_bf16(
                    afr, bfr[ni], acc[mi][ni], 0, 0, 0);
        }
        // single barrier per step is sufficient with double buffering:
        // buffer p is next written in step ks+2, after barrier ks+1 ordered
        // all step-ks readers past it.
    }

    // epilogue: C/D layout col=lane&15, row=(lane>>4)*4+reg
    const int lcol  = lane & 15;
    const int lrow4 = (lane >> 4) * 4;
    float bv[4];
    #pragma unroll
    for (int ni = 0; ni < 4; ++ni)
        bv[ni] = bias[(size_t)c * OUT_DIM + nt * BN + nbase + ni * 16 + lcol];

    #pragma unroll
    for (int mi = 0; mi < 8; ++mi) {
        int rbase = mbase + mi * 16 + lrow4;
        #pragma unroll
        for (int ni = 0; ni < 4; ++ni) {
            int ncol = nbase + ni * 16 + lcol;
            #pragma unroll
            for (int r = 0; r < 4; ++r) {
                Op[(size_t)(rbase + r) * OUT_DIM + ncol] = acc[mi][ni][r] + bv[ni];
            }
        }
    }
}

extern "C" void kernel_launch(void* const* d_in, const int* in_sizes, int n_in,
                              void* d_out, int out_size, void* d_ws, size_t ws_size,
                              hipStream_t stream) {
    const float* x      = (const float*)d_in[0];
    const int*   cid    = (const int*)d_in[1];
    const float* weight = (const float*)d_in[2];
    const float* bias   = (const float*)d_in[3];
    float* out = (float*)d_out;

    dim3 grid(256);     // flat: XCD-aware remap inside kernel
    dim3 block(512);
    hipLaunchKernelGGL(cslinear_kernel, grid, block, 0, stream,
                       x, cid, weight, bias, out);
}

// Round 5
// 57.037 us; speedup vs baseline: 2.2476x; 2.2476x over previous
//
#include <hip/hip_runtime.h>
#include <type_traits>

#define NUM_CATEGORIES 64
#define IN_DIM 1024
#define OUT_DIM 1024
#define BATCH 32
#define SEQ 512

#define BM 256
#define BN 256
#define BK 32
#define NSTEP (IN_DIM / BK)   // 32

#define LDA 40     // bf16 elems per A row (64B data + 16B pad), 16B-aligned
#define LDBW 260   // u32 words per B k-pair row (256 data + 4 pad), 16B-aligned

typedef float f32x4 __attribute__((ext_vector_type(4)));
typedef unsigned int u32x2 __attribute__((ext_vector_type(2)));
typedef unsigned int u32x4 __attribute__((ext_vector_type(4)));
typedef __bf16 bf16x8 __attribute__((ext_vector_type(8)));

__device__ inline unsigned int f2bf_rne(float f) {
    unsigned int u = __builtin_bit_cast(unsigned int, f);
    return (u + 0x7FFFu + ((u >> 16) & 1u)) >> 16;
}
__device__ inline unsigned int pack2(float lo, float hi) {
    return f2bf_rne(lo) | (f2bf_rne(hi) << 16);
}

__global__ __launch_bounds__(512, 2)
void cslinear_kernel(const float* __restrict__ x,
                     const int* __restrict__ cid,
                     const float* __restrict__ weight,
                     const float* __restrict__ bias,
                     float* __restrict__ out) {
    __shared__ unsigned short As[2][BM * LDA];          // 2 x 20 KB
    __shared__ unsigned int   Bs[2][(BK / 2) * LDBW];   // 2 x 16.25 KB

    const int t    = threadIdx.x;
    const int lane = t & 63;
    const int w    = t >> 6;      // 0..7

    // XCD-aware remap: dispatch slot s runs on XCD s%8 (round-robin).
    // Each XCD owns 4 whole batches (8 blocks each) -> x/W re-reads hit same L2.
    const int s    = blockIdx.x;      // 0..255
    const int xcd  = s & 7;
    const int ixd  = s >> 3;          // 0..31
    const int b    = xcd + 8 * (ixd >> 3);
    const int j    = ixd & 7;
    const int nt   = j & 3;           // 0..3
    const int mt   = j >> 2;          // 0..1

    const int c = cid[b];
    const float* Wp = weight + (size_t)c * IN_DIM * OUT_DIM + (size_t)nt * BN;
    const float* Xp = x + ((size_t)b * SEQ + (size_t)mt * BM) * IN_DIM;
    float* Op = out + ((size_t)b * SEQ + (size_t)mt * BM) * OUT_DIM + (size_t)nt * BN;

    f32x4 acc[8][4] = {};         // wave tile 128(m) x 64(n)

    const int mbase = (w >> 2) * 128;   // 0 or 128
    const int nbase = (w & 3) * 64;     // 0,64,128,192
    const int lrow  = lane & 15;
    const int lhi   = lane >> 4;        // 0..3 -> k-chunk

    // 2-deep staging sets — ALL indices compile-time (rule #20: runtime
    // indexing would demote these to scratch; that was R4's regression)
    f32x4 ra[2][4];
    f32x4 rb0[2][2], rb1[2][2];

    auto LOADT = [&](int ks, auto S) {
        constexpr int ss = decltype(S)::value;
        const float* Xk = Xp + ks * BK;
        #pragma unroll
        for (int i = 0; i < 4; ++i) {
            int f   = i * 512 + t;        // 0..2047
            int row = f >> 3;             // 0..255
            int c4  = f & 7;              // 0..7
            ra[ss][i] = *reinterpret_cast<const f32x4*>(Xk + (size_t)row * IN_DIM + c4 * 4);
        }
        const float* Wk = Wp + (size_t)(ks * BK) * OUT_DIM;
        #pragma unroll
        for (int i = 0; i < 2; ++i) {
            int u  = i * 512 + t;         // 0..1023
            int kp = u >> 6;              // 0..15
            int n4 = u & 63;              // 0..63
            const float* bse = Wk + (size_t)(2 * kp) * OUT_DIM + n4 * 4;
            rb0[ss][i] = *reinterpret_cast<const f32x4*>(bse);
            rb1[ss][i] = *reinterpret_cast<const f32x4*>(bse + OUT_DIM);
        }
    };

    auto STORET = [&](auto S) {
        constexpr int ss = decltype(S)::value;   // LDS buffer == staging set
        char* AsB = reinterpret_cast<char*>(&As[ss][0]);
        #pragma unroll
        for (int i = 0; i < 4; ++i) {
            int f   = i * 512 + t;
            int row = f >> 3;
            int c4  = f & 7;
            u32x2 q;
            q.x = pack2(ra[ss][i].x, ra[ss][i].y);
            q.y = pack2(ra[ss][i].z, ra[ss][i].w);
            *reinterpret_cast<u32x2*>(AsB + row * (LDA * 2) + c4 * 8) = q;
        }
        unsigned int* BsW = &Bs[ss][0];
        #pragma unroll
        for (int i = 0; i < 2; ++i) {
            int u  = i * 512 + t;
            int kp = u >> 6;
            int n4 = u & 63;
            u32x4 q;
            #pragma unroll
            for (int jj = 0; jj < 4; ++jj)
                q[jj] = pack2(rb0[ss][i][jj], rb1[ss][i][jj]);
            *reinterpret_cast<u32x4*>(BsW + kp * LDBW + n4 * 4) = q;  // contiguous b128
        }
    };

    auto COMPUTE = [&](auto S) {
        constexpr int ss = decltype(S)::value;
        const char* AsB = reinterpret_cast<const char*>(&As[ss][0]);
        const unsigned int* BsW = &Bs[ss][0];
        bf16x8 bfr[4];
        #pragma unroll
        for (int ni = 0; ni < 4; ++ni) {
            int n   = nbase + ni * 16 + lrow;
            int kp0 = lhi * 4;
            u32x4 wds;
            #pragma unroll
            for (int jj = 0; jj < 4; ++jj)
                wds[jj] = BsW[(kp0 + jj) * LDBW + n];
            bfr[ni] = __builtin_bit_cast(bf16x8, wds);
        }
        #pragma unroll
        for (int mi = 0; mi < 8; ++mi) {
            int r = mbase + mi * 16 + lrow;
            bf16x8 afr = *reinterpret_cast<const bf16x8*>(AsB + r * (LDA * 2) + lhi * 16);
            #pragma unroll
            for (int ni = 0; ni < 4; ++ni)
                acc[mi][ni] = __builtin_amdgcn_mfma_f32_16x16x32_bf16(
                    afr, bfr[ni], acc[mi][ni], 0, 0, 0);
        }
    };

    constexpr std::integral_constant<int, 0> S0{};
    constexpr std::integral_constant<int, 1> S1{};

    LOADT(0, S0);
    LOADT(1, S1);

    for (int ks = 0; ks < NSTEP; ks += 2) {
        // ---- even step: buffer/set 0 ----
        STORET(S0);                               // counted vmcnt wait (2-steps-old loads)
        if (ks + 2 < NSTEP) LOADT(ks + 2, S0);    // refill freed set, in flight 2 steps
        asm volatile("s_waitcnt lgkmcnt(0)" ::: "memory");
        __builtin_amdgcn_s_barrier();
        __builtin_amdgcn_sched_barrier(0);
        COMPUTE(S0);

        // ---- odd step: buffer/set 1 ----
        STORET(S1);
        if (ks + 3 < NSTEP) LOADT(ks + 3, S1);
        asm volatile("s_waitcnt lgkmcnt(0)" ::: "memory");
        __builtin_amdgcn_s_barrier();
        __builtin_amdgcn_sched_barrier(0);
        COMPUTE(S1);
        // single barrier per step is sufficient: buffer p is next written in
        // step ks+2, and barrier ks+1 orders all step-ks readers before it.
    }

    // epilogue: C/D layout col=lane&15, row=(lane>>4)*4+reg
    const int lcol  = lane & 15;
    const int lrow4 = (lane >> 4) * 4;
    float bv[4];
    #pragma unroll
    for (int ni = 0; ni < 4; ++ni)
        bv[ni] = bias[(size_t)c * OUT_DIM + nt * BN + nbase + ni * 16 + lcol];

    #pragma unroll
    for (int mi = 0; mi < 8; ++mi) {
        int rbase = mbase + mi * 16 + lrow4;
        #pragma unroll
        for (int ni = 0; ni < 4; ++ni) {
            int ncol = nbase + ni * 16 + lcol;
            #pragma unroll
            for (int r = 0; r < 4; ++r) {
                Op[(size_t)(rbase + r) * OUT_DIM + ncol] = acc[mi][ni][r] + bv[ni];
            }
        }
    }
}

extern "C" void kernel_launch(void* const* d_in, const int* in_sizes, int n_in,
                              void* d_out, int out_size, void* d_ws, size_t ws_size,
                              hipStream_t stream) {
    const float* x      = (const float*)d_in[0];
    const int*   cid    = (const int*)d_in[1];
    const float* weight = (const float*)d_in[2];
    const float* bias   = (const float*)d_in[3];
    float* out = (float*)d_out;

    dim3 grid(256);     // flat: XCD-aware remap inside kernel
    dim3 block(512);
    hipLaunchKernelGGL(cslinear_kernel, grid, block, 0, stream,
                       x, cid, weight, bias, out);
}